// Round 1
// 870.153 us; speedup vs baseline: 1.1352x; 1.1352x over previous
//
#include <hip/hip_runtime.h>
#include <hip/hip_bf16.h>
#include <cstdint>

typedef __hip_bfloat16 bf16;
typedef __hip_bfloat162 bf162;
typedef __bf16 bf16x8 __attribute__((ext_vector_type(8)));
typedef float f32x4 __attribute__((ext_vector_type(4)));

// ---------- dtype detection ----------
__global__ void detect_kernel(const unsigned short* __restrict__ xr, int* __restrict__ flag) {
  if (threadIdx.x == 0 && blockIdx.x == 0) {
    int pass = 0;
    for (int i = 0; i < 64; ++i) {
      unsigned short h = xr[2 * i];
      int e = (h >> 7) & 0xFF;
      if (e >= 110 && e <= 140) pass++;
    }
    *flag = (pass >= 32) ? 1 : 0;
  }
}

// ---------- batched weight conversion: 12 tensors in one launch ----------
struct CvtDesc {
  const void* src;
  void* dst;
  int n, fi, fo, mode;  // mode 1: transpose [fi][fo] -> bf16 [fo][fi]; mode 0: flat fp32
};
struct CvtAll { CvtDesc d[12]; };

__global__ void convert_all_kernel(CvtAll all, const int* __restrict__ flag) {
  CvtDesc dd = all.d[blockIdx.y];
  int isbf = *flag;
  for (int i = blockIdx.x * blockDim.x + threadIdx.x; i < dd.n; i += gridDim.x * blockDim.x) {
    float v = isbf ? __bfloat162float(((const bf16*)dd.src)[i]) : ((const float*)dd.src)[i];
    if (dd.mode) {
      int k = i / dd.fo, nn = i - k * dd.fo;
      ((__bf16*)dd.dst)[(size_t)nn * dd.fi + k] = (__bf16)v;
    } else {
      ((float*)dd.dst)[i] = v;
    }
  }
}

// ---------- graph preprocessing ----------

__global__ void count_kernel(const int* __restrict__ dst, int* __restrict__ deg, int E) {
  int i = blockIdx.x * blockDim.x + threadIdx.x;
  if (i < E) atomicAdd(&deg[dst[i]], 1);
}

__global__ void dinv_kernel(const int* __restrict__ deg, float* __restrict__ dinv, int n) {
  int i = blockIdx.x * blockDim.x + threadIdx.x;
  if (i < n) dinv[i] = rsqrtf((float)(deg[i] + 1));  // +1 self-loop
}

__global__ void scan_block_kernel(const int* __restrict__ counts, int* __restrict__ excl,
                                  int* __restrict__ bsum, int n) {
  __shared__ int sd[1024];
  int t = threadIdx.x;
  int i = blockIdx.x * 1024 + t;
  int v = (i < n) ? counts[i] : 0;
  sd[t] = v;
  __syncthreads();
  for (int off = 1; off < 1024; off <<= 1) {
    int x = (t >= off) ? sd[t - off] : 0;
    __syncthreads();
    sd[t] += x;
    __syncthreads();
  }
  if (i < n) excl[i] = sd[t] - v;
  if (t == 1023) bsum[blockIdx.x] = sd[1023];
}

__global__ void scan_sums_kernel(int* __restrict__ bsum, int nb, int* __restrict__ row_ptr, int n) {
  __shared__ int sd[1024];
  int t = threadIdx.x;
  int v = (t < nb) ? bsum[t] : 0;
  sd[t] = v;
  __syncthreads();
  for (int off = 1; off < 1024; off <<= 1) {
    int x = (t >= off) ? sd[t - off] : 0;
    __syncthreads();
    sd[t] += x;
    __syncthreads();
  }
  if (t < nb) bsum[t] = sd[t] - v;
  if (t == 1023) row_ptr[n] = sd[1023];
}

__global__ void scan_add_kernel(int* __restrict__ excl, const int* __restrict__ bsum, int n) {
  int i = blockIdx.x * blockDim.x + threadIdx.x;
  if (i < n) excl[i] += bsum[i >> 10];
}

__global__ void fill_kernel(const int* __restrict__ src, const int* __restrict__ dst,
                            const int* __restrict__ row_ptr, int* __restrict__ cursor,
                            int* __restrict__ col, int E) {
  int i = blockIdx.x * blockDim.x + threadIdx.x;
  if (i < E) {
    int d = dst[i];
    int pos = row_ptr[d] + atomicAdd(&cursor[d], 1);
    col[pos] = src[i];
  }
}

// ---------- MFMA GEMM, register double-buffered with STATIC indices ----------
// C[M,128] = A[M,K] @ Bt^T + bias; Bt: [128][K] bf16. No LDS (zero A reuse across
// blocks at N=128; Bt L2-resident). Wave: 64x64 via 4x4 of 16x16x32 MFMA.
// C/D layout: col=lane&15, row=quad*4+reg  [m89/m91].
// Round-4 lesson: runtime-indexed fragment arrays (a[cur][..]) get demoted to
// scratch -> MfmaUtil 0.17%, 3.1 ms. All buffer selection is compile-time here.

template <int K, int ADUAL>
__global__ __launch_bounds__(256) void gemm_mfma_kernel(
    const void* __restrict__ Ain, const __bf16* __restrict__ Bt,
    const float* __restrict__ bias, bf16* __restrict__ C,
    int M, const float* __restrict__ rowscale, int do_relu,
    const int* __restrict__ flag) {
  const int abf = ADUAL ? flag[0] : 1;  // 1 => A is bf16
  int t = threadIdx.x;
  int wave = t >> 6, lane = t & 63;
  int l15 = lane & 15, quad = lane >> 4;
  int wm = wave >> 1, wn = wave & 1;
  int rowbase = blockIdx.x * 128 + wm * 64;
  int colbase = wn * 64;
  const __bf16* Ab = (const __bf16*)Ain;
  const float* Af = (const float*)Ain;

  f32x4 acc[4][4];
#pragma unroll
  for (int mt = 0; mt < 4; ++mt)
#pragma unroll
    for (int nt = 0; nt < 4; ++nt) acc[mt][nt] = (f32x4){0.f, 0.f, 0.f, 0.f};

  int arow[4];
#pragma unroll
  for (int mt = 0; mt < 4; ++mt) {
    int r = rowbase + mt * 16 + l15;
    arow[mt] = (r < M) ? r : (M - 1);  // clamp; garbage rows masked at store
  }
  int brow[4];
#pragma unroll
  for (int nt = 0; nt < 4; ++nt) brow[nt] = colbase + nt * 16 + l15;

  bf16x8 aA[4], bA[4], aB[4], bB[4];

  auto load_chunk = [&](int kc, bf16x8 (&av)[4], bf16x8 (&bv)[4]) {
    int ko = kc + quad * 8;
    if (abf) {
#pragma unroll
      for (int mt = 0; mt < 4; ++mt)
        av[mt] = *(const bf16x8*)(Ab + (size_t)arow[mt] * K + ko);
    } else {
#pragma unroll
      for (int mt = 0; mt < 4; ++mt) {
        const float* p = Af + (size_t)arow[mt] * K + ko;
#pragma unroll
        for (int j = 0; j < 8; ++j) av[mt][j] = (__bf16)p[j];
      }
    }
#pragma unroll
    for (int nt = 0; nt < 4; ++nt)
      bv[nt] = *(const bf16x8*)(Bt + (size_t)brow[nt] * K + ko);
  };

  auto mfma16 = [&](const bf16x8 (&av)[4], const bf16x8 (&bv)[4]) {
#pragma unroll
    for (int mt = 0; mt < 4; ++mt)
#pragma unroll
      for (int nt = 0; nt < 4; ++nt)
        acc[mt][nt] =
            __builtin_amdgcn_mfma_f32_16x16x32_bf16(av[mt], bv[nt], acc[mt][nt], 0, 0, 0);
  };

  constexpr int NC = K / 32;  // 16 (K=512) or 4 (K=128); always even
  load_chunk(0, aA, bA);
#pragma unroll
  for (int c = 0; c < NC; c += 2) {
    if (c + 1 < NC) load_chunk((c + 1) * 32, aB, bB);
    mfma16(aA, bA);
    if (c + 2 < NC) load_chunk((c + 2) * 32, aA, bA);
    if (c + 1 < NC) mfma16(aB, bB);
  }

#pragma unroll
  for (int mt = 0; mt < 4; ++mt) {
    int r0 = rowbase + mt * 16 + quad * 4;
#pragma unroll
    for (int nt = 0; nt < 4; ++nt) {
      int c = colbase + nt * 16 + l15;
      float bs = bias[c];
#pragma unroll
      for (int i = 0; i < 4; ++i) {
        int r = r0 + i;
        if (r < M) {
          float v = acc[mt][nt][i] + bs;
          if (rowscale) v *= rowscale[r];
          if (do_relu) v = fmaxf(v, 0.f);
          C[(size_t)r * 128 + c] = __float2bfloat16(v);
        }
      }
    }
  }
}

// ---------- gather: y[d] = relu(dinv[d]*(g[d] + sum_{s in CSR[d]} g[s])) ----------
// 8-wide unroll with branchless tail masking: 8 col loads + 8 g-row loads in
// flight per wave (round-3 profile: VGPR=8, 1 outstanding load, ~1450 cyc/edge).

__global__ __launch_bounds__(256) void gather_kernel(
    const bf16* __restrict__ g, const int* __restrict__ row_ptr, const int* __restrict__ col,
    const float* __restrict__ dinv, bf16* __restrict__ y, int n) {
  int wave = threadIdx.x >> 6;
  int lane = threadIdx.x & 63;
  int node = blockIdx.x * 4 + wave;
  if (node >= n) return;
  const bf162* gp = (const bf162*)g;
  bf162 sv = gp[(size_t)node * 64 + lane];
  float ax = __bfloat162float(sv.x), ay = __bfloat162float(sv.y);
  float bx = 0.f, by = 0.f;
  int beg = row_ptr[node], end = row_ptr[node + 1];
  for (int e = beg; e < end; e += 8) {
    int s[8];
    float msk[8];
#pragma unroll
    for (int j = 0; j < 8; ++j) {
      int ee = e + j;
      bool ok = ee < end;
      s[j] = col[ok ? ee : e];  // e itself is always valid here
      msk[j] = ok ? 1.f : 0.f;
    }
    bf162 v[8];
#pragma unroll
    for (int j = 0; j < 8; ++j) v[j] = gp[(size_t)s[j] * 64 + lane];
#pragma unroll
    for (int j = 0; j < 8; j += 2) {
      ax = fmaf(msk[j], __bfloat162float(v[j].x), ax);
      ay = fmaf(msk[j], __bfloat162float(v[j].y), ay);
      bx = fmaf(msk[j + 1], __bfloat162float(v[j + 1].x), bx);
      by = fmaf(msk[j + 1], __bfloat162float(v[j + 1].y), by);
    }
  }
  float dv = dinv[node];
  float ox = fmaxf((ax + bx) * dv, 0.f);
  float oy = fmaxf((ay + by) * dv, 0.f);
  bf162 o;
  o.x = __float2bfloat16(ox);
  o.y = __float2bfloat16(oy);
  ((bf162*)y)[(size_t)node * 64 + lane] = o;
}

// ---------- fc3 (128->64) + log_softmax, MFMA version ----------
// Was: scalar 128-deep dependent-FMA chain per lane + 33KB LDS weight cache
// (143 us, MfmaUtil=0, 3.4% HBM, occupancy capped at 40%). Now: same 4x4
// 16x16x32 MFMA fragment structure as gemm_mfma_kernel, one wave = 64 rows x
// all 64 output cols (Wt: [64][128] bf16, K=128). After MFMA, row r's 64
// outputs live in 16 lanes (l15) x 4 regs (nt) within one quad group, so
// log-softmax max/sum are width-16 __shfl_xor reductions — fully parallel,
// no LDS.

__global__ __launch_bounds__(256) void fc3_softmax_mfma_kernel(
    const bf16* __restrict__ y, const __bf16* __restrict__ Wt,
    const float* __restrict__ b, void* __restrict__ out, int M,
    const int* __restrict__ flag) {
  const int isbf = flag[0];
  int t = threadIdx.x;
  int wave = t >> 6, lane = t & 63;
  int l15 = lane & 15, quad = lane >> 4;
  int rowbase = blockIdx.x * 256 + wave * 64;

  f32x4 acc[4][4];
#pragma unroll
  for (int mt = 0; mt < 4; ++mt)
#pragma unroll
    for (int nt = 0; nt < 4; ++nt) acc[mt][nt] = (f32x4){0.f, 0.f, 0.f, 0.f};

  int arow[4];
#pragma unroll
  for (int mt = 0; mt < 4; ++mt) {
    int r = rowbase + mt * 16 + l15;
    arow[mt] = (r < M) ? r : (M - 1);  // clamp; garbage rows never stored
  }

  bf16x8 aA[4], bA[4], aB[4], bB[4];

  auto load_chunk = [&](int kc, bf16x8 (&av)[4], bf16x8 (&bv)[4]) {
    int ko = kc + quad * 8;
#pragma unroll
    for (int mt = 0; mt < 4; ++mt)
      av[mt] = *(const bf16x8*)(y + (size_t)arow[mt] * 128 + ko);
#pragma unroll
    for (int nt = 0; nt < 4; ++nt)
      bv[nt] = *(const bf16x8*)(Wt + (size_t)(nt * 16 + l15) * 128 + ko);
  };

  auto mfma16 = [&](const bf16x8 (&av)[4], const bf16x8 (&bv)[4]) {
#pragma unroll
    for (int mt = 0; mt < 4; ++mt)
#pragma unroll
      for (int nt = 0; nt < 4; ++nt)
        acc[mt][nt] =
            __builtin_amdgcn_mfma_f32_16x16x32_bf16(av[mt], bv[nt], acc[mt][nt], 0, 0, 0);
  };

  // K=128 -> 4 chunks, register double-buffered, all static indices.
  load_chunk(0, aA, bA);
  load_chunk(32, aB, bB);
  mfma16(aA, bA);
  load_chunk(64, aA, bA);
  mfma16(aB, bB);
  load_chunk(96, aB, bB);
  mfma16(aA, bA);
  mfma16(aB, bB);

  float bcol[4];
#pragma unroll
  for (int nt = 0; nt < 4; ++nt) bcol[nt] = b[nt * 16 + l15];

#pragma unroll
  for (int mt = 0; mt < 4; ++mt) {
#pragma unroll
    for (int i = 0; i < 4; ++i) {
      int r = rowbase + mt * 16 + quad * 4 + i;
      float v0 = acc[mt][0][i] + bcol[0];
      float v1 = acc[mt][1][i] + bcol[1];
      float v2 = acc[mt][2][i] + bcol[2];
      float v3 = acc[mt][3][i] + bcol[3];
      float m = fmaxf(fmaxf(v0, v1), fmaxf(v2, v3));
#pragma unroll
      for (int off = 8; off > 0; off >>= 1) m = fmaxf(m, __shfl_xor(m, off, 16));
      float s = __expf(v0 - m) + __expf(v1 - m) + __expf(v2 - m) + __expf(v3 - m);
#pragma unroll
      for (int off = 8; off > 0; off >>= 1) s += __shfl_xor(s, off, 16);
      float ls = m + __logf(s);
      if (r < M) {
        if (isbf) {
          bf16* op = (bf16*)out + (size_t)r * 64 + l15;
          op[0] = __float2bfloat16(v0 - ls);
          op[16] = __float2bfloat16(v1 - ls);
          op[32] = __float2bfloat16(v2 - ls);
          op[48] = __float2bfloat16(v3 - ls);
        } else {
          float* op = (float*)out + (size_t)r * 64 + l15;
          op[0] = v0 - ls;
          op[16] = v1 - ls;
          op[32] = v2 - ls;
          op[48] = v3 - ls;
        }
      }
    }
  }
}

// ---------- launch ----------

extern "C" void kernel_launch(void* const* d_in, const int* in_sizes, int n_in,
                              void* d_out, int out_size, void* d_ws, size_t ws_size,
                              hipStream_t stream) {
  const void* x = d_in[0];
  const int* ei = (const int*)d_in[1];

  const int N = in_sizes[0] / 512;
  const int E = in_sizes[1] / 2;
  const int* srcp = ei;
  const int* dstp = ei + E;

  char* ws = (char*)d_ws;
  size_t off = 0;
  auto alloc = [&](size_t bytes) {
    void* p = ws + off;
    off = (off + bytes + 255) & ~(size_t)255;
    return p;
  };
  int*    flag    = (int*)alloc(4);
  int*    deg     = (int*)alloc((size_t)N * 4);
  int*    cursor  = (int*)alloc((size_t)N * 4);
  int*    row_ptr = (int*)alloc((size_t)(N + 1) * 4);
  int*    col     = (int*)alloc((size_t)E * 4);
  float*  dinv    = (float*)alloc((size_t)N * 4);
  int*    bsum    = (int*)alloc(1024 * 4);
  __bf16* W0t     = (__bf16*)alloc((size_t)512 * 128 * 2);
  __bf16* W1t     = (__bf16*)alloc((size_t)128 * 128 * 2);
  __bf16* W2t     = (__bf16*)alloc((size_t)128 * 128 * 2);
  __bf16* fc1t    = (__bf16*)alloc((size_t)128 * 128 * 2);
  __bf16* fc2t    = (__bf16*)alloc((size_t)128 * 128 * 2);
  __bf16* fc3t    = (__bf16*)alloc((size_t)64 * 128 * 2);
  float*  b0f     = (float*)alloc(128 * 4);
  float*  b1f     = (float*)alloc(128 * 4);
  float*  b2f     = (float*)alloc(128 * 4);
  float*  fc1bf   = (float*)alloc(128 * 4);
  float*  fc2bf   = (float*)alloc(128 * 4);
  float*  fc3bf   = (float*)alloc(64 * 4);
  bf16*   gbuf    = (bf16*)alloc((size_t)N * 128 * 2);
  bf16*   ybuf    = (bf16*)alloc((size_t)N * 128 * 2);

  const int tb = 256;

  detect_kernel<<<1, 64, 0, stream>>>((const unsigned short*)x, flag);

  CvtAll ca;
  ca.d[0]  = {d_in[2],  W0t,   512 * 128, 512, 128, 1};
  ca.d[1]  = {d_in[4],  W1t,   128 * 128, 128, 128, 1};
  ca.d[2]  = {d_in[6],  W2t,   128 * 128, 128, 128, 1};
  ca.d[3]  = {d_in[8],  fc1t,  128 * 128, 128, 128, 1};
  ca.d[4]  = {d_in[10], fc2t,  128 * 128, 128, 128, 1};
  ca.d[5]  = {d_in[3],  b0f,   128, 0, 0, 0};
  ca.d[6]  = {d_in[5],  b1f,   128, 0, 0, 0};
  ca.d[7]  = {d_in[7],  b2f,   128, 0, 0, 0};
  ca.d[8]  = {d_in[9],  fc1bf, 128, 0, 0, 0};
  ca.d[9]  = {d_in[11], fc2bf, 128, 0, 0, 0};
  ca.d[10] = {d_in[12], fc3t,  128 * 64, 128, 64, 1};
  ca.d[11] = {d_in[13], fc3bf, 64, 0, 0, 0};
  convert_all_kernel<<<dim3(64, 12), 256, 0, stream>>>(ca, flag);

  hipMemsetAsync(deg, 0, (size_t)N * 4, stream);
  hipMemsetAsync(cursor, 0, (size_t)N * 4, stream);

  count_kernel<<<(E + tb - 1) / tb, tb, 0, stream>>>(dstp, deg, E);
  dinv_kernel<<<(N + tb - 1) / tb, tb, 0, stream>>>(deg, dinv, N);
  int nb = (N + 1023) / 1024;
  scan_block_kernel<<<nb, 1024, 0, stream>>>(deg, row_ptr, bsum, N);
  scan_sums_kernel<<<1, 1024, 0, stream>>>(bsum, nb, row_ptr, N);
  scan_add_kernel<<<(N + tb - 1) / tb, tb, 0, stream>>>(row_ptr, bsum, N);
  fill_kernel<<<(E + tb - 1) / tb, tb, 0, stream>>>(srcp, dstp, row_ptr, cursor, col, E);

  int gemm_blocks = (N + 127) / 128;
  int gat_blocks = (N + 3) / 4;
  int fc3_blocks = (N + 255) / 256;

  // conv0
  gemm_mfma_kernel<512, 1><<<gemm_blocks, 256, 0, stream>>>(x, W0t, b0f, gbuf, N, dinv, 0, flag);
  gather_kernel<<<gat_blocks, 256, 0, stream>>>(gbuf, row_ptr, col, dinv, ybuf, N);
  // conv1
  gemm_mfma_kernel<128, 0><<<gemm_blocks, 256, 0, stream>>>(ybuf, W1t, b1f, gbuf, N, dinv, 0, flag);
  gather_kernel<<<gat_blocks, 256, 0, stream>>>(gbuf, row_ptr, col, dinv, ybuf, N);
  // conv2
  gemm_mfma_kernel<128, 0><<<gemm_blocks, 256, 0, stream>>>(ybuf, W2t, b2f, gbuf, N, dinv, 0, flag);
  gather_kernel<<<gat_blocks, 256, 0, stream>>>(gbuf, row_ptr, col, dinv, ybuf, N);
  // fc1 (ybuf -> gbuf), fc2 (gbuf -> ybuf)
  gemm_mfma_kernel<128, 0><<<gemm_blocks, 256, 0, stream>>>(ybuf, fc1t, fc1bf, gbuf, N, nullptr, 1, flag);
  gemm_mfma_kernel<128, 0><<<gemm_blocks, 256, 0, stream>>>(gbuf, fc2t, fc2bf, ybuf, N, nullptr, 1, flag);
  // fc3 + log_softmax (MFMA)
  fc3_softmax_mfma_kernel<<<fc3_blocks, 256, 0, stream>>>(ybuf, fc3t, fc3bf, d_out, N, flag);
}

// Round 3
// 828.221 us; speedup vs baseline: 1.1927x; 1.0506x over previous
//
#include <hip/hip_runtime.h>
#include <hip/hip_bf16.h>
#include <cstdint>

typedef __hip_bfloat16 bf16;
typedef __hip_bfloat162 bf162;
typedef __bf16 bf16x8 __attribute__((ext_vector_type(8)));
typedef float f32x4 __attribute__((ext_vector_type(4)));

// ---------- dtype detection ----------
__global__ void detect_kernel(const unsigned short* __restrict__ xr, int* __restrict__ flag) {
  if (threadIdx.x == 0 && blockIdx.x == 0) {
    int pass = 0;
    for (int i = 0; i < 64; ++i) {
      unsigned short h = xr[2 * i];
      int e = (h >> 7) & 0xFF;
      if (e >= 110 && e <= 140) pass++;
    }
    *flag = (pass >= 32) ? 1 : 0;
  }
}

// ---------- batched weight conversion: 12 tensors in one launch ----------
struct CvtDesc {
  const void* src;
  void* dst;
  int n, fi, fo, mode;  // mode 1: transpose [fi][fo] -> bf16 [fo][fi]; mode 0: flat fp32
};
struct CvtAll { CvtDesc d[12]; };

__global__ void convert_all_kernel(CvtAll all, const int* __restrict__ flag) {
  CvtDesc dd = all.d[blockIdx.y];
  int isbf = *flag;
  for (int i = blockIdx.x * blockDim.x + threadIdx.x; i < dd.n; i += gridDim.x * blockDim.x) {
    float v = isbf ? __bfloat162float(((const bf16*)dd.src)[i]) : ((const float*)dd.src)[i];
    if (dd.mode) {
      int k = i / dd.fo, nn = i - k * dd.fo;
      ((__bf16*)dd.dst)[(size_t)nn * dd.fi + k] = (__bf16)v;
    } else {
      ((float*)dd.dst)[i] = v;
    }
  }
}

// ---------- graph preprocessing ----------

__global__ void count_kernel(const int* __restrict__ dst, int* __restrict__ deg, int E) {
  int i = blockIdx.x * blockDim.x + threadIdx.x;
  if (i < E) atomicAdd(&deg[dst[i]], 1);
}

__global__ void dinv_kernel(const int* __restrict__ deg, float* __restrict__ dinv, int n) {
  int i = blockIdx.x * blockDim.x + threadIdx.x;
  if (i < n) dinv[i] = rsqrtf((float)(deg[i] + 1));  // +1 self-loop
}

__global__ void scan_block_kernel(const int* __restrict__ counts, int* __restrict__ excl,
                                  int* __restrict__ bsum, int n) {
  __shared__ int sd[1024];
  int t = threadIdx.x;
  int i = blockIdx.x * 1024 + t;
  int v = (i < n) ? counts[i] : 0;
  sd[t] = v;
  __syncthreads();
  for (int off = 1; off < 1024; off <<= 1) {
    int x = (t >= off) ? sd[t - off] : 0;
    __syncthreads();
    sd[t] += x;
    __syncthreads();
  }
  if (i < n) excl[i] = sd[t] - v;
  if (t == 1023) bsum[blockIdx.x] = sd[1023];
}

__global__ void scan_sums_kernel(int* __restrict__ bsum, int nb, int* __restrict__ row_ptr, int n) {
  __shared__ int sd[1024];
  int t = threadIdx.x;
  int v = (t < nb) ? bsum[t] : 0;
  sd[t] = v;
  __syncthreads();
  for (int off = 1; off < 1024; off <<= 1) {
    int x = (t >= off) ? sd[t - off] : 0;
    __syncthreads();
    sd[t] += x;
    __syncthreads();
  }
  if (t < nb) bsum[t] = sd[t] - v;
  if (t == 1023) row_ptr[n] = sd[1023];
}

__global__ void scan_add_kernel(int* __restrict__ excl, const int* __restrict__ bsum, int n) {
  int i = blockIdx.x * blockDim.x + threadIdx.x;
  if (i < n) excl[i] += bsum[i >> 10];
}

__global__ void fill_kernel(const int* __restrict__ src, const int* __restrict__ dst,
                            const int* __restrict__ row_ptr, int* __restrict__ cursor,
                            int* __restrict__ col, int E) {
  int i = blockIdx.x * blockDim.x + threadIdx.x;
  if (i < E) {
    int d = dst[i];
    int pos = row_ptr[d] + atomicAdd(&cursor[d], 1);
    col[pos] = src[i];
  }
}

// ---------- async global->LDS helper (16B, literal size per guide) ----------
__device__ __forceinline__ void gload_lds16(const void* g, void* l) {
  __builtin_amdgcn_global_load_lds(
      (const __attribute__((address_space(1))) void*)g,
      (__attribute__((address_space(3))) void*)l, 16, 0, 0);
}

// ---------- MFMA GEMM, m97-style LDS-staged 2-phase pipeline ----------
// C[M,128] = A[M,K] @ Bt^T + bias; Bt: [128][K] bf16.
// Round-1 profile (no-LDS version): conv0 = 138us, hbm 940 GB/s (11.7%),
// MfmaUtil 3.6%, VALUBusy 5.5% -> pure latency-bound; register-dependent
// loads cap in-flight bytes. Fix: BK=64 double-buffered LDS staging via
// global_load_lds (async DMA, 32KB/block in flight per K-step), 2-phase
// loop {issue next-tile DMA; ds_read+MFMA current; barrier}.
// LDS tiles [128 rows][64 bf16] (128B rows) are same-bank on ds_read_b128
// across rows -> XOR swizzle slot^(row&7), applied as pre-swizzled GLOBAL
// source + swizzled read addr, LDS dest stays linear (rule #21: gload_lds
// writes firstlane-base+lane*16 only; our per-lane dest ptrs are exactly
// that). Residual 2-way aliasing is free (m136).
// Wave: 64x64 quadrant via 4x4 of 16x16x32 MFMA; C/D layout col=lane&15,
// row=quad*4+reg [m89/m91]. LDS 64KB -> 2 blocks/CU.
// Round-2 container died without counters: likely infra, but hardened the
// one kernel-side suspect -- LDS tiles now __align__(16) (DMA writes 16B,
// ds_read_b128 reads 16B; natural bf16 alignment is only 2B).

template <int K, int ADUAL>
__global__ __launch_bounds__(256) void gemm_mfma_kernel(
    const void* __restrict__ Ain, const __bf16* __restrict__ Bt,
    const float* __restrict__ bias, bf16* __restrict__ C,
    int M, const float* __restrict__ rowscale, int do_relu,
    const int* __restrict__ flag) {
  constexpr int BK = 64;        // K-elems per tile (128B rows in LDS)
  constexpr int NT = K / BK;    // 8 (K=512) or 2 (K=128)
  __shared__ __align__(16) __bf16 As[2][128 * BK];  // 16KB per buffer
  __shared__ __align__(16) __bf16 Bs[2][128 * BK];

  const int abf = ADUAL ? flag[0] : 1;  // 1 => A is bf16
  int t = threadIdx.x;
  int wave = t >> 6, lane = t & 63;
  int l15 = lane & 15, quad = lane >> 4;
  int wm = wave >> 1, wn = wave & 1;
  int rowbase = blockIdx.x * 128;
  const __bf16* Ab = (const __bf16*)Ain;
  const float* Af = (const float*)Ain;

  // staging decomposition: thread t covers LDS row srow(+32 per inst), slot sslot
  int srow = t >> 3;       // 0..31
  int sslot = t & 7;       // 16B slot within 128B row
  int xslot = sslot ^ (srow & 7);  // pre-swizzled source slot

  int sArow[4];  // clamped global A rows for the 4 staging insts
#pragma unroll
  for (int i = 0; i < 4; ++i) {
    int r = rowbase + i * 32 + srow;
    sArow[i] = (r < M) ? r : (M - 1);  // dup loads harmless; masked at store
  }

  f32x4 acc[4][4];
#pragma unroll
  for (int mt = 0; mt < 4; ++mt)
#pragma unroll
    for (int nt = 0; nt < 4; ++nt) acc[mt][nt] = (f32x4){0.f, 0.f, 0.f, 0.f};

  auto stage = [&](int kt, int buf) {
    int kbase = kt * BK + xslot * 8;  // element offset incl. swizzled slot
    if (abf) {
#pragma unroll
      for (int i = 0; i < 4; ++i)
        gload_lds16(Ab + (size_t)sArow[i] * K + kbase, &As[buf][t * 8 + i * 2048]);
    } else {
#pragma unroll
      for (int i = 0; i < 4; ++i) {
        const float* p = Af + (size_t)sArow[i] * K + kbase;
        bf16x8 v;
#pragma unroll
        for (int j = 0; j < 8; ++j) v[j] = (__bf16)p[j];
        *(bf16x8*)&As[buf][t * 8 + i * 2048] = v;
      }
    }
#pragma unroll
    for (int i = 0; i < 4; ++i)
      gload_lds16(Bt + (size_t)(i * 32 + srow) * K + kbase, &Bs[buf][t * 8 + i * 2048]);
  };

  auto compute = [&](int buf) {
#pragma unroll
    for (int c = 0; c < 2; ++c) {  // two K=32 chunks per BK=64 tile
      bf16x8 av[4], bv[4];
#pragma unroll
      for (int mt = 0; mt < 4; ++mt) {
        int row = wm * 64 + mt * 16 + l15;
        int slot = (c * 4 + quad) ^ (row & 7);
        av[mt] = *(const bf16x8*)&As[buf][row * BK + slot * 8];
      }
#pragma unroll
      for (int nt = 0; nt < 4; ++nt) {
        int row = wn * 64 + nt * 16 + l15;
        int slot = (c * 4 + quad) ^ (row & 7);
        bv[nt] = *(const bf16x8*)&Bs[buf][row * BK + slot * 8];
      }
#pragma unroll
      for (int mt = 0; mt < 4; ++mt)
#pragma unroll
        for (int nt = 0; nt < 4; ++nt)
          acc[mt][nt] =
              __builtin_amdgcn_mfma_f32_16x16x32_bf16(av[mt], bv[nt], acc[mt][nt], 0, 0, 0);
    }
  };

  stage(0, 0);
  __syncthreads();  // drains vmcnt(0): tile 0 resident
#pragma unroll
  for (int kt = 0; kt < NT; ++kt) {
    int cur = kt & 1;
    if (kt + 1 < NT) stage(kt + 1, cur ^ 1);  // async DMA flies under compute
    compute(cur);
    __syncthreads();  // vmcnt(0)+barrier: next tile ready, cur reusable
  }

#pragma unroll
  for (int mt = 0; mt < 4; ++mt) {
    int r0 = rowbase + wm * 64 + mt * 16 + quad * 4;
#pragma unroll
    for (int nt = 0; nt < 4; ++nt) {
      int c = wn * 64 + nt * 16 + l15;
      float bs = bias[c];
#pragma unroll
      for (int i = 0; i < 4; ++i) {
        int r = r0 + i;
        if (r < M) {
          float v = acc[mt][nt][i] + bs;
          if (rowscale) v *= rowscale[r];
          if (do_relu) v = fmaxf(v, 0.f);
          C[(size_t)r * 128 + c] = __float2bfloat16(v);
        }
      }
    }
  }
}

// ---------- gather: y[d] = relu(dinv[d]*(g[d] + sum_{s in CSR[d]} g[s])) ----------
// 8-wide unroll with branchless tail masking: 8 col loads + 8 g-row loads in
// flight per wave.

__global__ __launch_bounds__(256) void gather_kernel(
    const bf16* __restrict__ g, const int* __restrict__ row_ptr, const int* __restrict__ col,
    const float* __restrict__ dinv, bf16* __restrict__ y, int n) {
  int wave = threadIdx.x >> 6;
  int lane = threadIdx.x & 63;
  int node = blockIdx.x * 4 + wave;
  if (node >= n) return;
  const bf162* gp = (const bf162*)g;
  bf162 sv = gp[(size_t)node * 64 + lane];
  float ax = __bfloat162float(sv.x), ay = __bfloat162float(sv.y);
  float bx = 0.f, by = 0.f;
  int beg = row_ptr[node], end = row_ptr[node + 1];
  for (int e = beg; e < end; e += 8) {
    int s[8];
    float msk[8];
#pragma unroll
    for (int j = 0; j < 8; ++j) {
      int ee = e + j;
      bool ok = ee < end;
      s[j] = col[ok ? ee : e];  // e itself is always valid here
      msk[j] = ok ? 1.f : 0.f;
    }
    bf162 v[8];
#pragma unroll
    for (int j = 0; j < 8; ++j) v[j] = gp[(size_t)s[j] * 64 + lane];
#pragma unroll
    for (int j = 0; j < 8; j += 2) {
      ax = fmaf(msk[j], __bfloat162float(v[j].x), ax);
      ay = fmaf(msk[j], __bfloat162float(v[j].y), ay);
      bx = fmaf(msk[j + 1], __bfloat162float(v[j + 1].x), bx);
      by = fmaf(msk[j + 1], __bfloat162float(v[j + 1].y), by);
    }
  }
  float dv = dinv[node];
  float ox = fmaxf((ax + bx) * dv, 0.f);
  float oy = fmaxf((ay + by) * dv, 0.f);
  bf162 o;
  o.x = __float2bfloat16(ox);
  o.y = __float2bfloat16(oy);
  ((bf162*)y)[(size_t)node * 64 + lane] = o;
}

// ---------- fc3 (128->64) + log_softmax, MFMA version ----------
// One wave = 64 rows x all 64 output cols (Wt: [64][128] bf16, K=128).
// Row r's 64 outputs live in 16 lanes (l15) x 4 regs (nt) within one quad
// group, so log-softmax max/sum are width-16 __shfl_xor reductions.

__global__ __launch_bounds__(256) void fc3_softmax_mfma_kernel(
    const bf16* __restrict__ y, const __bf16* __restrict__ Wt,
    const float* __restrict__ b, void* __restrict__ out, int M,
    const int* __restrict__ flag) {
  const int isbf = flag[0];
  int t = threadIdx.x;
  int wave = t >> 6, lane = t & 63;
  int l15 = lane & 15, quad = lane >> 4;
  int rowbase = blockIdx.x * 256 + wave * 64;

  f32x4 acc[4][4];
#pragma unroll
  for (int mt = 0; mt < 4; ++mt)
#pragma unroll
    for (int nt = 0; nt < 4; ++nt) acc[mt][nt] = (f32x4){0.f, 0.f, 0.f, 0.f};

  int arow[4];
#pragma unroll
  for (int mt = 0; mt < 4; ++mt) {
    int r = rowbase + mt * 16 + l15;
    arow[mt] = (r < M) ? r : (M - 1);  // clamp; garbage rows never stored
  }

  bf16x8 aA[4], bA[4], aB[4], bB[4];

  auto load_chunk = [&](int kc, bf16x8 (&av)[4], bf16x8 (&bv)[4]) {
    int ko = kc + quad * 8;
#pragma unroll
    for (int mt = 0; mt < 4; ++mt)
      av[mt] = *(const bf16x8*)(y + (size_t)arow[mt] * 128 + ko);
#pragma unroll
    for (int nt = 0; nt < 4; ++nt)
      bv[nt] = *(const bf16x8*)(Wt + (size_t)(nt * 16 + l15) * 128 + ko);
  };

  auto mfma16 = [&](const bf16x8 (&av)[4], const bf16x8 (&bv)[4]) {
#pragma unroll
    for (int mt = 0; mt < 4; ++mt)
#pragma unroll
      for (int nt = 0; nt < 4; ++nt)
        acc[mt][nt] =
            __builtin_amdgcn_mfma_f32_16x16x32_bf16(av[mt], bv[nt], acc[mt][nt], 0, 0, 0);
  };

  // K=128 -> 4 chunks, register double-buffered, all static indices.
  load_chunk(0, aA, bA);
  load_chunk(32, aB, bB);
  mfma16(aA, bA);
  load_chunk(64, aA, bA);
  mfma16(aB, bB);
  load_chunk(96, aB, bB);
  mfma16(aA, bA);
  mfma16(aB, bB);

  float bcol[4];
#pragma unroll
  for (int nt = 0; nt < 4; ++nt) bcol[nt] = b[nt * 16 + l15];

#pragma unroll
  for (int mt = 0; mt < 4; ++mt) {
#pragma unroll
    for (int i = 0; i < 4; ++i) {
      int r = rowbase + mt * 16 + quad * 4 + i;
      float v0 = acc[mt][0][i] + bcol[0];
      float v1 = acc[mt][1][i] + bcol[1];
      float v2 = acc[mt][2][i] + bcol[2];
      float v3 = acc[mt][3][i] + bcol[3];
      float m = fmaxf(fmaxf(v0, v1), fmaxf(v2, v3));
#pragma unroll
      for (int off = 8; off > 0; off >>= 1) m = fmaxf(m, __shfl_xor(m, off, 16));
      float s = __expf(v0 - m) + __expf(v1 - m) + __expf(v2 - m) + __expf(v3 - m);
#pragma unroll
      for (int off = 8; off > 0; off >>= 1) s += __shfl_xor(s, off, 16);
      float ls = m + __logf(s);
      if (r < M) {
        if (isbf) {
          bf16* op = (bf16*)out + (size_t)r * 64 + l15;
          op[0] = __float2bfloat16(v0 - ls);
          op[16] = __float2bfloat16(v1 - ls);
          op[32] = __float2bfloat16(v2 - ls);
          op[48] = __float2bfloat16(v3 - ls);
        } else {
          float* op = (float*)out + (size_t)r * 64 + l15;
          op[0] = v0 - ls;
          op[16] = v1 - ls;
          op[32] = v2 - ls;
          op[48] = v3 - ls;
        }
      }
    }
  }
}

// ---------- launch ----------

extern "C" void kernel_launch(void* const* d_in, const int* in_sizes, int n_in,
                              void* d_out, int out_size, void* d_ws, size_t ws_size,
                              hipStream_t stream) {
  const void* x = d_in[0];
  const int* ei = (const int*)d_in[1];

  const int N = in_sizes[0] / 512;
  const int E = in_sizes[1] / 2;
  const int* srcp = ei;
  const int* dstp = ei + E;

  char* ws = (char*)d_ws;
  size_t off = 0;
  auto alloc = [&](size_t bytes) {
    void* p = ws + off;
    off = (off + bytes + 255) & ~(size_t)255;
    return p;
  };
  int*    flag    = (int*)alloc(4);
  int*    deg     = (int*)alloc((size_t)N * 4);
  int*    cursor  = (int*)alloc((size_t)N * 4);
  int*    row_ptr = (int*)alloc((size_t)(N + 1) * 4);
  int*    col     = (int*)alloc((size_t)E * 4);
  float*  dinv    = (float*)alloc((size_t)N * 4);
  int*    bsum    = (int*)alloc(1024 * 4);
  __bf16* W0t     = (__bf16*)alloc((size_t)512 * 128 * 2);
  __bf16* W1t     = (__bf16*)alloc((size_t)128 * 128 * 2);
  __bf16* W2t     = (__bf16*)alloc((size_t)128 * 128 * 2);
  __bf16* fc1t    = (__bf16*)alloc((size_t)128 * 128 * 2);
  __bf16* fc2t    = (__bf16*)alloc((size_t)128 * 128 * 2);
  __bf16* fc3t    = (__bf16*)alloc((size_t)64 * 128 * 2);
  float*  b0f     = (float*)alloc(128 * 4);
  float*  b1f     = (float*)alloc(128 * 4);
  float*  b2f     = (float*)alloc(128 * 4);
  float*  fc1bf   = (float*)alloc(128 * 4);
  float*  fc2bf   = (float*)alloc(128 * 4);
  float*  fc3bf   = (float*)alloc(64 * 4);
  bf16*   gbuf    = (bf16*)alloc((size_t)N * 128 * 2);
  bf16*   ybuf    = (bf16*)alloc((size_t)N * 128 * 2);

  const int tb = 256;

  detect_kernel<<<1, 64, 0, stream>>>((const unsigned short*)x, flag);

  CvtAll ca;
  ca.d[0]  = {d_in[2],  W0t,   512 * 128, 512, 128, 1};
  ca.d[1]  = {d_in[4],  W1t,   128 * 128, 128, 128, 1};
  ca.d[2]  = {d_in[6],  W2t,   128 * 128, 128, 128, 1};
  ca.d[3]  = {d_in[8],  fc1t,  128 * 128, 128, 128, 1};
  ca.d[4]  = {d_in[10], fc2t,  128 * 128, 128, 128, 1};
  ca.d[5]  = {d_in[3],  b0f,   128, 0, 0, 0};
  ca.d[6]  = {d_in[5],  b1f,   128, 0, 0, 0};
  ca.d[7]  = {d_in[7],  b2f,   128, 0, 0, 0};
  ca.d[8]  = {d_in[9],  fc1bf, 128, 0, 0, 0};
  ca.d[9]  = {d_in[11], fc2bf, 128, 0, 0, 0};
  ca.d[10] = {d_in[12], fc3t,  128 * 64, 128, 64, 1};
  ca.d[11] = {d_in[13], fc3bf, 64, 0, 0, 0};
  convert_all_kernel<<<dim3(64, 12), 256, 0, stream>>>(ca, flag);

  hipMemsetAsync(deg, 0, (size_t)N * 4, stream);
  hipMemsetAsync(cursor, 0, (size_t)N * 4, stream);

  count_kernel<<<(E + tb - 1) / tb, tb, 0, stream>>>(dstp, deg, E);
  dinv_kernel<<<(N + tb - 1) / tb, tb, 0, stream>>>(deg, dinv, N);
  int nb = (N + 1023) / 1024;
  scan_block_kernel<<<nb, 1024, 0, stream>>>(deg, row_ptr, bsum, N);
  scan_sums_kernel<<<1, 1024, 0, stream>>>(bsum, nb, row_ptr, N);
  scan_add_kernel<<<(N + tb - 1) / tb, tb, 0, stream>>>(row_ptr, bsum, N);
  fill_kernel<<<(E + tb - 1) / tb, tb, 0, stream>>>(srcp, dstp, row_ptr, cursor, col, E);

  int gemm_blocks = (N + 127) / 128;
  int gat_blocks = (N + 3) / 4;
  int fc3_blocks = (N + 255) / 256;

  // conv0
  gemm_mfma_kernel<512, 1><<<gemm_blocks, 256, 0, stream>>>(x, W0t, b0f, gbuf, N, dinv, 0, flag);
  gather_kernel<<<gat_blocks, 256, 0, stream>>>(gbuf, row_ptr, col, dinv, ybuf, N);
  // conv1
  gemm_mfma_kernel<128, 0><<<gemm_blocks, 256, 0, stream>>>(ybuf, W1t, b1f, gbuf, N, dinv, 0, flag);
  gather_kernel<<<gat_blocks, 256, 0, stream>>>(gbuf, row_ptr, col, dinv, ybuf, N);
  // conv2
  gemm_mfma_kernel<128, 0><<<gemm_blocks, 256, 0, stream>>>(ybuf, W2t, b2f, gbuf, N, dinv, 0, flag);
  gather_kernel<<<gat_blocks, 256, 0, stream>>>(gbuf, row_ptr, col, dinv, ybuf, N);
  // fc1 (ybuf -> gbuf), fc2 (gbuf -> ybuf)
  gemm_mfma_kernel<128, 0><<<gemm_blocks, 256, 0, stream>>>(ybuf, fc1t, fc1bf, gbuf, N, nullptr, 1, flag);
  gemm_mfma_kernel<128, 0><<<gemm_blocks, 256, 0, stream>>>(gbuf, fc2t, fc2bf, ybuf, N, nullptr, 1, flag);
  // fc3 + log_softmax (MFMA)
  fc3_softmax_mfma_kernel<<<fc3_blocks, 256, 0, stream>>>(ybuf, fc3t, fc3bf, d_out, N, flag);
}

// Round 4
// 808.396 us; speedup vs baseline: 1.2220x; 1.0245x over previous
//
#include <hip/hip_runtime.h>
#include <hip/hip_bf16.h>
#include <cstdint>

typedef __hip_bfloat16 bf16;
typedef __hip_bfloat162 bf162;
typedef __bf16 bf16x8 __attribute__((ext_vector_type(8)));
typedef float f32x4 __attribute__((ext_vector_type(4)));

// ---------- dtype detection ----------
__global__ void detect_kernel(const unsigned short* __restrict__ xr, int* __restrict__ flag) {
  if (threadIdx.x == 0 && blockIdx.x == 0) {
    int pass = 0;
    for (int i = 0; i < 64; ++i) {
      unsigned short h = xr[2 * i];
      int e = (h >> 7) & 0xFF;
      if (e >= 110 && e <= 140) pass++;
    }
    *flag = (pass >= 32) ? 1 : 0;
  }
}

// ---------- batched weight conversion: 12 tensors in one launch ----------
struct CvtDesc {
  const void* src;
  void* dst;
  int n, fi, fo, mode;  // mode 1: transpose [fi][fo] -> bf16 [fo][fi]; mode 0: flat fp32
};
struct CvtAll { CvtDesc d[12]; };

__global__ void convert_all_kernel(CvtAll all, const int* __restrict__ flag) {
  CvtDesc dd = all.d[blockIdx.y];
  int isbf = *flag;
  for (int i = blockIdx.x * blockDim.x + threadIdx.x; i < dd.n; i += gridDim.x * blockDim.x) {
    float v = isbf ? __bfloat162float(((const bf16*)dd.src)[i]) : ((const float*)dd.src)[i];
    if (dd.mode) {
      int k = i / dd.fo, nn = i - k * dd.fo;
      ((__bf16*)dd.dst)[(size_t)nn * dd.fi + k] = (__bf16)v;
    } else {
      ((float*)dd.dst)[i] = v;
    }
  }
}

// ---------- graph preprocessing ----------

__global__ void count_kernel(const int* __restrict__ dst, int* __restrict__ deg, int E) {
  int i = blockIdx.x * blockDim.x + threadIdx.x;
  if (i < E) atomicAdd(&deg[dst[i]], 1);
}

__global__ void dinv_kernel(const int* __restrict__ deg, float* __restrict__ dinv, int n) {
  int i = blockIdx.x * blockDim.x + threadIdx.x;
  if (i < n) dinv[i] = rsqrtf((float)(deg[i] + 1));  // +1 self-loop
}

__global__ void scan_block_kernel(const int* __restrict__ counts, int* __restrict__ excl,
                                  int* __restrict__ bsum, int n) {
  __shared__ int sd[1024];
  int t = threadIdx.x;
  int i = blockIdx.x * 1024 + t;
  int v = (i < n) ? counts[i] : 0;
  sd[t] = v;
  __syncthreads();
  for (int off = 1; off < 1024; off <<= 1) {
    int x = (t >= off) ? sd[t - off] : 0;
    __syncthreads();
    sd[t] += x;
    __syncthreads();
  }
  if (i < n) excl[i] = sd[t] - v;
  if (t == 1023) bsum[blockIdx.x] = sd[1023];
}

__global__ void scan_sums_kernel(int* __restrict__ bsum, int nb, int* __restrict__ row_ptr, int n) {
  __shared__ int sd[1024];
  int t = threadIdx.x;
  int v = (t < nb) ? bsum[t] : 0;
  sd[t] = v;
  __syncthreads();
  for (int off = 1; off < 1024; off <<= 1) {
    int x = (t >= off) ? sd[t - off] : 0;
    __syncthreads();
    sd[t] += x;
    __syncthreads();
  }
  if (t < nb) bsum[t] = sd[t] - v;
  if (t == 1023) row_ptr[n] = sd[1023];
}

__global__ void scan_add_kernel(int* __restrict__ excl, const int* __restrict__ bsum, int n) {
  int i = blockIdx.x * blockDim.x + threadIdx.x;
  if (i < n) excl[i] += bsum[i >> 10];
}

__global__ void fill_kernel(const int* __restrict__ src, const int* __restrict__ dst,
                            const int* __restrict__ row_ptr, int* __restrict__ cursor,
                            int* __restrict__ col, int E) {
  int i = blockIdx.x * blockDim.x + threadIdx.x;
  if (i < E) {
    int d = dst[i];
    int pos = row_ptr[d] + atomicAdd(&cursor[d], 1);
    col[pos] = src[i];
  }
}

// ---------- async global->LDS helper (16B, literal size per guide) ----------
__device__ __forceinline__ void gload_lds16(const void* g, void* l) {
  __builtin_amdgcn_global_load_lds(
      (const __attribute__((address_space(1))) void*)g,
      (__attribute__((address_space(3))) void*)l, 16, 0, 0);
}

// ---------- MFMA GEMM, m97-style LDS-staged 2-phase pipeline ----------
// C[M,128] = A[M,K] @ Bt^T + bias; Bt: [128][K] bf16.
// BK=64 double-buffered LDS staging via global_load_lds; XOR swizzle
// slot^(row&7) applied as pre-swizzled GLOBAL source + swizzled read addr,
// LDS dest linear (rule #21). Wave: 64x64 quadrant via 4x4 of 16x16x32
// MFMA; C/D layout col=lane&15, row=quad*4+reg [m89/m91].

template <int K, int ADUAL>
__global__ __launch_bounds__(256) void gemm_mfma_kernel(
    const void* __restrict__ Ain, const __bf16* __restrict__ Bt,
    const float* __restrict__ bias, bf16* __restrict__ C,
    int M, const float* __restrict__ rowscale, int do_relu,
    const int* __restrict__ flag) {
  constexpr int BK = 64;        // K-elems per tile (128B rows in LDS)
  constexpr int NT = K / BK;    // 8 (K=512) or 2 (K=128)
  __shared__ __align__(16) __bf16 As[2][128 * BK];  // 16KB per buffer
  __shared__ __align__(16) __bf16 Bs[2][128 * BK];

  const int abf = ADUAL ? flag[0] : 1;  // 1 => A is bf16
  int t = threadIdx.x;
  int wave = t >> 6, lane = t & 63;
  int l15 = lane & 15, quad = lane >> 4;
  int wm = wave >> 1, wn = wave & 1;
  int rowbase = blockIdx.x * 128;
  const __bf16* Ab = (const __bf16*)Ain;
  const float* Af = (const float*)Ain;

  // staging decomposition: thread t covers LDS row srow(+32 per inst), slot sslot
  int srow = t >> 3;       // 0..31
  int sslot = t & 7;       // 16B slot within 128B row
  int xslot = sslot ^ (srow & 7);  // pre-swizzled source slot

  int sArow[4];  // clamped global A rows for the 4 staging insts
#pragma unroll
  for (int i = 0; i < 4; ++i) {
    int r = rowbase + i * 32 + srow;
    sArow[i] = (r < M) ? r : (M - 1);  // dup loads harmless; masked at store
  }

  f32x4 acc[4][4];
#pragma unroll
  for (int mt = 0; mt < 4; ++mt)
#pragma unroll
    for (int nt = 0; nt < 4; ++nt) acc[mt][nt] = (f32x4){0.f, 0.f, 0.f, 0.f};

  auto stage = [&](int kt, int buf) {
    int kbase = kt * BK + xslot * 8;  // element offset incl. swizzled slot
    if (abf) {
#pragma unroll
      for (int i = 0; i < 4; ++i)
        gload_lds16(Ab + (size_t)sArow[i] * K + kbase, &As[buf][t * 8 + i * 2048]);
    } else {
#pragma unroll
      for (int i = 0; i < 4; ++i) {
        const float* p = Af + (size_t)sArow[i] * K + kbase;
        bf16x8 v;
#pragma unroll
        for (int j = 0; j < 8; ++j) v[j] = (__bf16)p[j];
        *(bf16x8*)&As[buf][t * 8 + i * 2048] = v;
      }
    }
#pragma unroll
    for (int i = 0; i < 4; ++i)
      gload_lds16(Bt + (size_t)(i * 32 + srow) * K + kbase, &Bs[buf][t * 8 + i * 2048]);
  };

  auto compute = [&](int buf) {
#pragma unroll
    for (int c = 0; c < 2; ++c) {  // two K=32 chunks per BK=64 tile
      bf16x8 av[4], bv[4];
#pragma unroll
      for (int mt = 0; mt < 4; ++mt) {
        int row = wm * 64 + mt * 16 + l15;
        int slot = (c * 4 + quad) ^ (row & 7);
        av[mt] = *(const bf16x8*)&As[buf][row * BK + slot * 8];
      }
#pragma unroll
      for (int nt = 0; nt < 4; ++nt) {
        int row = wn * 64 + nt * 16 + l15;
        int slot = (c * 4 + quad) ^ (row & 7);
        bv[nt] = *(const bf16x8*)&Bs[buf][row * BK + slot * 8];
      }
#pragma unroll
      for (int mt = 0; mt < 4; ++mt)
#pragma unroll
        for (int nt = 0; nt < 4; ++nt)
          acc[mt][nt] =
              __builtin_amdgcn_mfma_f32_16x16x32_bf16(av[mt], bv[nt], acc[mt][nt], 0, 0, 0);
    }
  };

  stage(0, 0);
  __syncthreads();  // drains vmcnt(0): tile 0 resident
#pragma unroll
  for (int kt = 0; kt < NT; ++kt) {
    int cur = kt & 1;
    if (kt + 1 < NT) stage(kt + 1, cur ^ 1);  // async DMA flies under compute
    compute(cur);
    __syncthreads();  // vmcnt(0)+barrier: next tile ready, cur reusable
  }

#pragma unroll
  for (int mt = 0; mt < 4; ++mt) {
    int r0 = rowbase + wm * 64 + mt * 16 + quad * 4;
#pragma unroll
    for (int nt = 0; nt < 4; ++nt) {
      int c = wn * 64 + nt * 16 + l15;
      float bs = bias[c];
#pragma unroll
      for (int i = 0; i < 4; ++i) {
        int r = r0 + i;
        if (r < M) {
          float v = acc[mt][nt][i] + bs;
          if (rowscale) v *= rowscale[r];
          if (do_relu) v = fmaxf(v, 0.f);
          C[(size_t)r * 128 + c] = __float2bfloat16(v);
        }
      }
    }
  }
}

// ---------- gather: y[d] = relu(dinv[d]*(g[d] + sum_{s in CSR[d]} g[s])) ----------
// 8-wide unroll with branchless tail masking: 8 col loads + 8 g-row loads in
// flight per wave. (Untouched this round for clean delta attribution.)

__global__ __launch_bounds__(256) void gather_kernel(
    const bf16* __restrict__ g, const int* __restrict__ row_ptr, const int* __restrict__ col,
    const float* __restrict__ dinv, bf16* __restrict__ y, int n) {
  int wave = threadIdx.x >> 6;
  int lane = threadIdx.x & 63;
  int node = blockIdx.x * 4 + wave;
  if (node >= n) return;
  const bf162* gp = (const bf162*)g;
  bf162 sv = gp[(size_t)node * 64 + lane];
  float ax = __bfloat162float(sv.x), ay = __bfloat162float(sv.y);
  float bx = 0.f, by = 0.f;
  int beg = row_ptr[node], end = row_ptr[node + 1];
  for (int e = beg; e < end; e += 8) {
    int s[8];
    float msk[8];
#pragma unroll
    for (int j = 0; j < 8; ++j) {
      int ee = e + j;
      bool ok = ee < end;
      s[j] = col[ok ? ee : e];  // e itself is always valid here
      msk[j] = ok ? 1.f : 0.f;
    }
    bf162 v[8];
#pragma unroll
    for (int j = 0; j < 8; ++j) v[j] = gp[(size_t)s[j] * 64 + lane];
#pragma unroll
    for (int j = 0; j < 8; j += 2) {
      ax = fmaf(msk[j], __bfloat162float(v[j].x), ax);
      ay = fmaf(msk[j], __bfloat162float(v[j].y), ay);
      bx = fmaf(msk[j + 1], __bfloat162float(v[j + 1].x), bx);
      by = fmaf(msk[j + 1], __bfloat162float(v[j + 1].y), by);
    }
  }
  float dv = dinv[node];
  float ox = fmaxf((ax + bx) * dv, 0.f);
  float oy = fmaxf((ay + by) * dv, 0.f);
  bf162 o;
  o.x = __float2bfloat16(ox);
  o.y = __float2bfloat16(oy);
  ((bf162*)y)[(size_t)node * 64 + lane] = o;
}

// ---------- fused FC chain: out = log_softmax(relu(relu(y@W1+b1)@W2+b2)@W3+b3) ----------
// All three FC layers are row-local -> fuse per 128-row block. Eliminates the
// fc1/fc2 intermediate round-trips (2 x 51.2 MB) + fc3's global input read
// (25.6 MB) + 2 kernel launches. Phase 1 reads ybuf from global (L3-resident,
// just written by gather2) with the proven reg-double-buffered K=128 MFMA
// structure; phases 2/3 read A-fragments from LDS.
// LDS h-tiles padded to 136 elems/row (272B = 17*16B): keeps ds_read_b128
// 16B-aligned, row-to-row bank advance of 4 -> ~2-way residual aliasing
// (free, m136). 69.6 KB LDS -> 2 blocks/CU.
// Phase-3: wave w owns rows w*32..w*32+31 (mt<2), all 64 cols; softmax
// reductions are width-16 __shfl_xor within each quad (row r's 64 outputs
// live in 16 lanes x 4 regs).

__global__ __launch_bounds__(256) void fc_chain_kernel(
    const bf16* __restrict__ yin, const __bf16* __restrict__ W1t,
    const float* __restrict__ b1, const __bf16* __restrict__ W2t,
    const float* __restrict__ b2, const __bf16* __restrict__ W3t,
    const float* __restrict__ b3, void* __restrict__ out, int M,
    const int* __restrict__ flag) {
  constexpr int LDH = 136;  // padded row stride in elems
  __shared__ __align__(16) __bf16 h1[128 * LDH];
  __shared__ __align__(16) __bf16 h2[128 * LDH];
  const int isbf = flag[0];
  int t = threadIdx.x;
  int wave = t >> 6, lane = t & 63;
  int l15 = lane & 15, quad = lane >> 4;
  int wm = wave >> 1, wn = wave & 1;
  int rowbase = blockIdx.x * 128;

  f32x4 acc[4][4];
  bf16x8 aA[4], bA[4], aB[4], bB[4];

  auto zacc = [&]() {
#pragma unroll
    for (int mt = 0; mt < 4; ++mt)
#pragma unroll
      for (int nt = 0; nt < 4; ++nt) acc[mt][nt] = (f32x4){0.f, 0.f, 0.f, 0.f};
  };
  auto mfma16 = [&](const bf16x8 (&av)[4], const bf16x8 (&bv)[4]) {
#pragma unroll
    for (int mt = 0; mt < 4; ++mt)
#pragma unroll
      for (int nt = 0; nt < 4; ++nt)
        acc[mt][nt] =
            __builtin_amdgcn_mfma_f32_16x16x32_bf16(av[mt], bv[nt], acc[mt][nt], 0, 0, 0);
  };

  // ---- phase 1: h1 = relu(yin @ W1t^T + b1), A from global ----
  int arow[4];
#pragma unroll
  for (int mt = 0; mt < 4; ++mt) {
    int r = rowbase + wm * 64 + mt * 16 + l15;
    arow[mt] = (r < M) ? r : (M - 1);  // clamp; dup rows never stored to out
  }
  auto ld1 = [&](int kc, bf16x8 (&av)[4], bf16x8 (&bv)[4]) {
    int ko = kc + quad * 8;
#pragma unroll
    for (int mt = 0; mt < 4; ++mt)
      av[mt] = *(const bf16x8*)(yin + (size_t)arow[mt] * 128 + ko);
#pragma unroll
    for (int nt = 0; nt < 4; ++nt)
      bv[nt] = *(const bf16x8*)(W1t + (size_t)(wn * 64 + nt * 16 + l15) * 128 + ko);
  };
  zacc();
  ld1(0, aA, bA);
  ld1(32, aB, bB);
  mfma16(aA, bA);
  ld1(64, aA, bA);
  mfma16(aB, bB);
  ld1(96, aB, bB);
  mfma16(aA, bA);
  mfma16(aB, bB);
#pragma unroll
  for (int mt = 0; mt < 4; ++mt) {
    int rl0 = wm * 64 + mt * 16 + quad * 4;
#pragma unroll
    for (int nt = 0; nt < 4; ++nt) {
      int c = wn * 64 + nt * 16 + l15;
      float bs = b1[c];
#pragma unroll
      for (int i = 0; i < 4; ++i)
        h1[(rl0 + i) * LDH + c] = (__bf16)fmaxf(acc[mt][nt][i] + bs, 0.f);
    }
  }
  __syncthreads();

  // ---- phase 2: h2 = relu(h1 @ W2t^T + b2), A from LDS ----
  auto ld2 = [&](int kc, bf16x8 (&av)[4], bf16x8 (&bv)[4]) {
    int ko = kc + quad * 8;
#pragma unroll
    for (int mt = 0; mt < 4; ++mt)
      av[mt] = *(const bf16x8*)&h1[(wm * 64 + mt * 16 + l15) * LDH + ko];
#pragma unroll
    for (int nt = 0; nt < 4; ++nt)
      bv[nt] = *(const bf16x8*)(W2t + (size_t)(wn * 64 + nt * 16 + l15) * 128 + ko);
  };
  zacc();
  ld2(0, aA, bA);
  ld2(32, aB, bB);
  mfma16(aA, bA);
  ld2(64, aA, bA);
  mfma16(aB, bB);
  ld2(96, aB, bB);
  mfma16(aA, bA);
  mfma16(aB, bB);
#pragma unroll
  for (int mt = 0; mt < 4; ++mt) {
    int rl0 = wm * 64 + mt * 16 + quad * 4;
#pragma unroll
    for (int nt = 0; nt < 4; ++nt) {
      int c = wn * 64 + nt * 16 + l15;
      float bs = b2[c];
#pragma unroll
      for (int i = 0; i < 4; ++i)
        h2[(rl0 + i) * LDH + c] = (__bf16)fmaxf(acc[mt][nt][i] + bs, 0.f);
    }
  }
  __syncthreads();

  // ---- phase 3: out = log_softmax(h2 @ W3t^T + b3), wave w -> rows w*32.. ----
  f32x4 acc3[2][4];
#pragma unroll
  for (int mt = 0; mt < 2; ++mt)
#pragma unroll
    for (int nt = 0; nt < 4; ++nt) acc3[mt][nt] = (f32x4){0.f, 0.f, 0.f, 0.f};
  bf16x8 a3A[2], a3B[2];
  auto ld3 = [&](int kc, bf16x8 (&av)[2], bf16x8 (&bv)[4]) {
    int ko = kc + quad * 8;
#pragma unroll
    for (int mt = 0; mt < 2; ++mt)
      av[mt] = *(const bf16x8*)&h2[(wave * 32 + mt * 16 + l15) * LDH + ko];
#pragma unroll
    for (int nt = 0; nt < 4; ++nt)
      bv[nt] = *(const bf16x8*)(W3t + (size_t)(nt * 16 + l15) * 128 + ko);
  };
  auto mfma8 = [&](const bf16x8 (&av)[2], const bf16x8 (&bv)[4]) {
#pragma unroll
    for (int mt = 0; mt < 2; ++mt)
#pragma unroll
      for (int nt = 0; nt < 4; ++nt)
        acc3[mt][nt] =
            __builtin_amdgcn_mfma_f32_16x16x32_bf16(av[mt], bv[nt], acc3[mt][nt], 0, 0, 0);
  };
  ld3(0, a3A, bA);
  ld3(32, a3B, bB);
  mfma8(a3A, bA);
  ld3(64, a3A, bA);
  mfma8(a3B, bB);
  ld3(96, a3B, bB);
  mfma8(a3A, bA);
  mfma8(a3B, bB);

  float bcol[4];
#pragma unroll
  for (int nt = 0; nt < 4; ++nt) bcol[nt] = b3[nt * 16 + l15];

#pragma unroll
  for (int mt = 0; mt < 2; ++mt) {
#pragma unroll
    for (int i = 0; i < 4; ++i) {
      int r = rowbase + wave * 32 + mt * 16 + quad * 4 + i;
      float v0 = acc3[mt][0][i] + bcol[0];
      float v1 = acc3[mt][1][i] + bcol[1];
      float v2 = acc3[mt][2][i] + bcol[2];
      float v3 = acc3[mt][3][i] + bcol[3];
      float m = fmaxf(fmaxf(v0, v1), fmaxf(v2, v3));
#pragma unroll
      for (int off = 8; off > 0; off >>= 1) m = fmaxf(m, __shfl_xor(m, off, 16));
      float s = __expf(v0 - m) + __expf(v1 - m) + __expf(v2 - m) + __expf(v3 - m);
#pragma unroll
      for (int off = 8; off > 0; off >>= 1) s += __shfl_xor(s, off, 16);
      float ls = m + __logf(s);
      if (r < M) {
        if (isbf) {
          bf16* op = (bf16*)out + (size_t)r * 64 + l15;
          op[0] = __float2bfloat16(v0 - ls);
          op[16] = __float2bfloat16(v1 - ls);
          op[32] = __float2bfloat16(v2 - ls);
          op[48] = __float2bfloat16(v3 - ls);
        } else {
          float* op = (float*)out + (size_t)r * 64 + l15;
          op[0] = v0 - ls;
          op[16] = v1 - ls;
          op[32] = v2 - ls;
          op[48] = v3 - ls;
        }
      }
    }
  }
}

// ---------- launch ----------

extern "C" void kernel_launch(void* const* d_in, const int* in_sizes, int n_in,
                              void* d_out, int out_size, void* d_ws, size_t ws_size,
                              hipStream_t stream) {
  const void* x = d_in[0];
  const int* ei = (const int*)d_in[1];

  const int N = in_sizes[0] / 512;
  const int E = in_sizes[1] / 2;
  const int* srcp = ei;
  const int* dstp = ei + E;

  char* ws = (char*)d_ws;
  size_t off = 0;
  auto alloc = [&](size_t bytes) {
    void* p = ws + off;
    off = (off + bytes + 255) & ~(size_t)255;
    return p;
  };
  int*    flag    = (int*)alloc(4);
  int*    deg     = (int*)alloc((size_t)N * 4);
  int*    cursor  = (int*)alloc((size_t)N * 4);
  int*    row_ptr = (int*)alloc((size_t)(N + 1) * 4);
  int*    col     = (int*)alloc((size_t)E * 4);
  float*  dinv    = (float*)alloc((size_t)N * 4);
  int*    bsum    = (int*)alloc(1024 * 4);
  __bf16* W0t     = (__bf16*)alloc((size_t)512 * 128 * 2);
  __bf16* W1t     = (__bf16*)alloc((size_t)128 * 128 * 2);
  __bf16* W2t     = (__bf16*)alloc((size_t)128 * 128 * 2);
  __bf16* fc1t    = (__bf16*)alloc((size_t)128 * 128 * 2);
  __bf16* fc2t    = (__bf16*)alloc((size_t)128 * 128 * 2);
  __bf16* fc3t    = (__bf16*)alloc((size_t)64 * 128 * 2);
  float*  b0f     = (float*)alloc(128 * 4);
  float*  b1f     = (float*)alloc(128 * 4);
  float*  b2f     = (float*)alloc(128 * 4);
  float*  fc1bf   = (float*)alloc(128 * 4);
  float*  fc2bf   = (float*)alloc(128 * 4);
  float*  fc3bf   = (float*)alloc(64 * 4);
  bf16*   gbuf    = (bf16*)alloc((size_t)N * 128 * 2);
  bf16*   ybuf    = (bf16*)alloc((size_t)N * 128 * 2);

  const int tb = 256;

  detect_kernel<<<1, 64, 0, stream>>>((const unsigned short*)x, flag);

  CvtAll ca;
  ca.d[0]  = {d_in[2],  W0t,   512 * 128, 512, 128, 1};
  ca.d[1]  = {d_in[4],  W1t,   128 * 128, 128, 128, 1};
  ca.d[2]  = {d_in[6],  W2t,   128 * 128, 128, 128, 1};
  ca.d[3]  = {d_in[8],  fc1t,  128 * 128, 128, 128, 1};
  ca.d[4]  = {d_in[10], fc2t,  128 * 128, 128, 128, 1};
  ca.d[5]  = {d_in[3],  b0f,   128, 0, 0, 0};
  ca.d[6]  = {d_in[5],  b1f,   128, 0, 0, 0};
  ca.d[7]  = {d_in[7],  b2f,   128, 0, 0, 0};
  ca.d[8]  = {d_in[9],  fc1bf, 128, 0, 0, 0};
  ca.d[9]  = {d_in[11], fc2bf, 128, 0, 0, 0};
  ca.d[10] = {d_in[12], fc3t,  128 * 64, 128, 64, 1};
  ca.d[11] = {d_in[13], fc3bf, 64, 0, 0, 0};
  convert_all_kernel<<<dim3(64, 12), 256, 0, stream>>>(ca, flag);

  hipMemsetAsync(deg, 0, (size_t)N * 4, stream);
  hipMemsetAsync(cursor, 0, (size_t)N * 4, stream);

  count_kernel<<<(E + tb - 1) / tb, tb, 0, stream>>>(dstp, deg, E);
  dinv_kernel<<<(N + tb - 1) / tb, tb, 0, stream>>>(deg, dinv, N);
  int nb = (N + 1023) / 1024;
  scan_block_kernel<<<nb, 1024, 0, stream>>>(deg, row_ptr, bsum, N);
  scan_sums_kernel<<<1, 1024, 0, stream>>>(bsum, nb, row_ptr, N);
  scan_add_kernel<<<(N + tb - 1) / tb, tb, 0, stream>>>(row_ptr, bsum, N);
  fill_kernel<<<(E + tb - 1) / tb, tb, 0, stream>>>(srcp, dstp, row_ptr, cursor, col, E);

  int gemm_blocks = (N + 127) / 128;
  int gat_blocks = (N + 3) / 4;

  // conv0
  gemm_mfma_kernel<512, 1><<<gemm_blocks, 256, 0, stream>>>(x, W0t, b0f, gbuf, N, dinv, 0, flag);
  gather_kernel<<<gat_blocks, 256, 0, stream>>>(gbuf, row_ptr, col, dinv, ybuf, N);
  // conv1
  gemm_mfma_kernel<128, 0><<<gemm_blocks, 256, 0, stream>>>(ybuf, W1t, b1f, gbuf, N, dinv, 0, flag);
  gather_kernel<<<gat_blocks, 256, 0, stream>>>(gbuf, row_ptr, col, dinv, ybuf, N);
  // conv2
  gemm_mfma_kernel<128, 0><<<gemm_blocks, 256, 0, stream>>>(ybuf, W2t, b2f, gbuf, N, dinv, 0, flag);
  gather_kernel<<<gat_blocks, 256, 0, stream>>>(gbuf, row_ptr, col, dinv, ybuf, N);
  // fused fc1+fc2+fc3+log_softmax
  fc_chain_kernel<<<gemm_blocks, 256, 0, stream>>>(ybuf, fc1t, fc1bf, fc2t, fc2bf,
                                                   fc3t, fc3bf, d_out, N, flag);
}